// Round 15
// baseline (493.479 us; speedup 1.0000x reference)
//
#include <hip/hip_runtime.h>

typedef unsigned short u16;
typedef unsigned int u32;

#define NB 8
#define NCH 192
#define NC3 576
#define NHW 16384
#define NHEADS 8

typedef __attribute__((ext_vector_type(8))) short s16x8;
typedef __attribute__((ext_vector_type(4))) float f32x4;

__device__ __forceinline__ float bf2f(u32 h) {
  return __uint_as_float(h << 16);
}
// packed RNE f32x2 -> bf16x2 (single HW instruction; identical rounding to the
// old shift/add f2bf, so results are bitwise unchanged)
__device__ __forceinline__ u32 cvtpk(float lo, float hi) {
  u32 r;
  asm("v_cvt_pk_bf16_f32 %0, %1, %2" : "=v"(r) : "v"(lo), "v"(hi));
  return r;
}
__device__ __forceinline__ u16 f2bf(float f) { return (u16)cvtpk(f, f); }

// XOR swizzle within a 128-byte LDS row.
__device__ __forceinline__ int swz(int row) { return ((row >> 1) & 7) << 4; }

__device__ __forceinline__ void gl_lds16(const void* g, void* s) {
  __builtin_amdgcn_global_load_lds((const __attribute__((address_space(1))) unsigned int*)g,
                                   (__attribute__((address_space(3))) unsigned int*)s, 16, 0, 0);
}

// ---------------------------------------------------------------------------
// cast conv weights fp32 -> bf16; zero norms2 and G accumulators
// ---------------------------------------------------------------------------
__global__ __launch_bounds__(256) void wcast_kernel(
    const float* __restrict__ w1, const float* __restrict__ w2,
    u16* __restrict__ o1, u16* __restrict__ o2, float* __restrict__ norms2,
    float* __restrict__ G) {
  int i = blockIdx.x * 256 + threadIdx.x;
  if (i < NC3 * NCH) {
    o1[i] = f2bf(w1[i]);
    o2[i] = f2bf(w2[i]);
  }
  if (i < 4 * NB * NCH) norms2[i] = 0.f;
  if (i < NB * NHEADS * 2304) G[i] = 0.f;
}

// ---------------------------------------------------------------------------
// conv1x1 MFMA, MERGED both modalities: 6144 blocks, modality from block id.
// 40KB LDS (A single 24KB via gl_lds @0, B single 16KB @24576).
// Per K-step: a_glds(t); b_write(t); b_load(t+1); barrier; MFMA(t); barrier.
// ---------------------------------------------------------------------------
__device__ __forceinline__ void conv_b_load(const float* __restrict__ x, int b, int nbase,
                                            int kb, int w, int l, float2 (&val)[16]) {
  const float* xr = x + (((size_t)(b * NCH + kb + w * 16)) << 14) + nbase + l * 2;
#pragma unroll
  for (int jj = 0; jj < 16; ++jj)
    val[jj] = *(const float2*)(xr + ((size_t)jj << 14));
}

__device__ __forceinline__ void conv_b_write(char* smem, int w, int l,
                                             const float2 (&val)[16]) {
#pragma unroll
  for (int nn = 0; nn < 2; ++nn) {
    const int row = l * 2 + nn;
    u32 p[8];
#pragma unroll
    for (int q = 0; q < 8; ++q) {
      const float a = nn ? val[2 * q].y : val[2 * q].x;
      const float bb = nn ? val[2 * q + 1].y : val[2 * q + 1].x;
      p[q] = cvtpk(a, bb);
    }
    char* base = smem + 24576 + row * 128;
    *(uint4*)(base + ((w * 32 + 0) ^ swz(row))) = make_uint4(p[0], p[1], p[2], p[3]);
    *(uint4*)(base + ((w * 32 + 16) ^ swz(row))) = make_uint4(p[4], p[5], p[6], p[7]);
  }
}

__device__ __forceinline__ void conv_a_glds(char* smem, const u16* __restrict__ wbf,
                                            int obase, int kb, int w, int l) {
#pragma unroll
  for (int i = 0; i < 6; ++i) {
    const int grp = i * 4 + w;
    const int row = grp * 8 + (l >> 3);
    const int cb = ((l & 7) * 16) ^ swz(row);
    const char* src = (const char*)wbf + (size_t)(obase + row) * 384 + kb * 2 + cb;
    gl_lds16(src, smem + grp * 1024);
  }
}

__global__ __launch_bounds__(256) void conv_mfma_kernel(
    const float* __restrict__ x1, const u16* __restrict__ wbf1, u16* __restrict__ pre1,
    const float* __restrict__ x2, const u16* __restrict__ wbf2, u16* __restrict__ pre2) {
  __shared__ char smem[40960];
  const int bid = blockIdx.x;                      // 6144 blocks
  const int id = (bid & 7) * 768 + (bid >> 3);     // bijective XCD chunk
  const int mod = (id >= 3072) ? 1 : 0;
  const int idm = id - mod * 3072;
  const float* x = mod ? x2 : x1;
  const u16* wbf = mod ? wbf2 : wbf1;
  u16* pre = mod ? pre2 : pre1;
  const int b = idm / 384;
  const int rr = idm % 384;
  const int nbase = (rr / 3) * 128;
  const int obase = (rr % 3) * 192;
  const int tid = threadIdx.x;
  const int w = tid >> 6, l = tid & 63;
  const int wr = w >> 1, wc = w & 1;

  f32x4 acc[6][4];
#pragma unroll
  for (int m = 0; m < 6; ++m)
#pragma unroll
    for (int nf = 0; nf < 4; ++nf) acc[m][nf] = (f32x4)0.f;

  float2 fB[16];
  conv_b_load(x, b, nbase, 0, w, l, fB);

  for (int t = 0; t < 3; ++t) {
    conv_a_glds(smem, wbf, obase, t * 64, w, l);
    conv_b_write(smem, w, l, fB);
    if (t < 2) conv_b_load(x, b, nbase, (t + 1) * 64, w, l, fB);  // issue early
    __syncthreads();  // A(t), B(t) resident
#pragma unroll
    for (int kk = 0; kk < 2; ++kk) {
      s16x8 a[6], bv[4];
      const int cbk = kk * 64 + (l >> 4) * 16;
#pragma unroll
      for (int m = 0; m < 6; ++m) {
        const int rowA = wr * 96 + m * 16 + (l & 15);
        a[m] = *(const s16x8*)(smem + rowA * 128 + (cbk ^ swz(rowA)));
      }
#pragma unroll
      for (int nf = 0; nf < 4; ++nf) {
        const int rowB = wc * 64 + nf * 16 + (l & 15);
        bv[nf] = *(const s16x8*)(smem + 24576 + rowB * 128 + (cbk ^ swz(rowB)));
      }
#pragma unroll
      for (int m = 0; m < 6; ++m)
#pragma unroll
        for (int nf = 0; nf < 4; ++nf)
          acc[m][nf] = __builtin_amdgcn_mfma_f32_16x16x32_bf16(a[m], bv[nf], acc[m][nf], 0, 0, 0);
    }
    __syncthreads();  // all waves done reading before next overwrite
  }
  // epilogue: per-wave LDS transpose ([16][72] u16), then 16B stores.
  u16* cw = (u16*)(smem) + w * 16 * 72;
#pragma unroll
  for (int m = 0; m < 6; ++m) {
#pragma unroll
    for (int nf = 0; nf < 4; ++nf)
#pragma unroll
      for (int r = 0; r < 2; ++r) {
        const u32 pk = cvtpk(acc[m][nf][2 * r], acc[m][nf][2 * r + 1]);
        cw[((l >> 4) * 4 + 2 * r) * 72 + nf * 16 + (l & 15)] = (u16)pk;
        cw[((l >> 4) * 4 + 2 * r + 1) * 72 + nf * 16 + (l & 15)] = (u16)(pk >> 16);
      }
#pragma unroll
    for (int p = 0; p < 2; ++p) {
      const int chunk = p * 64 + l;
      const int row = chunk >> 3, cg = chunk & 7;
      uint4 v = *(const uint4*)(cw + row * 72 + cg * 8);
      const int o = obase + wr * 96 + m * 16 + row;
      const int n = nbase + wc * 64 + cg * 8;
      *(uint4*)(pre + (((size_t)b * NC3 + o) << 14) + n) = v;
    }
  }
}

// ---------------------------------------------------------------------------
// depthwise 3x3, 2 output rows x 8 px per thread (halo amp 2x)
// + fused sum-of-squares for q,k planes. cvt_pk packed output.
// ---------------------------------------------------------------------------
__device__ __forceinline__ void dw_body(float* red, const u16* __restrict__ in,
                                        const float* __restrict__ wdw, u16* __restrict__ out,
                                        float* __restrict__ norms2, const int mod,
                                        const size_t t, const int tid) {
  const int l = tid & 63;
  const int xc = (int)(t & 15);
  const int yp = (int)((t >> 4) & 63);
  const int bc = (int)(t >> 10);
  const int c = bc % NC3;
  const int b = bc / NC3;
  const u16* p = in + ((size_t)bc << 14);
  const float* wc = wdw + c * 9;
  const int x0 = xc * 8;
  const int y0 = yp * 2;

  float a[4][10];
#pragma unroll
  for (int r = 0; r < 4; ++r) {
    const int y2 = y0 + r - 1;
    if ((unsigned)y2 < 128u) {
      const u16* row = p + (y2 << 7);
      uint4 v = *(const uint4*)(row + x0);
      a[r][1] = bf2f(v.x & 0xffff); a[r][2] = bf2f(v.x >> 16);
      a[r][3] = bf2f(v.y & 0xffff); a[r][4] = bf2f(v.y >> 16);
      a[r][5] = bf2f(v.z & 0xffff); a[r][6] = bf2f(v.z >> 16);
      a[r][7] = bf2f(v.w & 0xffff); a[r][8] = bf2f(v.w >> 16);
    } else {
#pragma unroll
      for (int j = 1; j < 9; ++j) a[r][j] = 0.f;
    }
    const float lf = __shfl(a[r][8], (l - 1) & 63, 64);
    const float rt = __shfl(a[r][1], (l + 1) & 63, 64);
    a[r][0] = (xc > 0) ? lf : 0.f;
    a[r][9] = (xc < 15) ? rt : 0.f;
  }
  const float w00 = wc[0], w01 = wc[1], w02 = wc[2];
  const float w10 = wc[3], w11 = wc[4], w12 = wc[5];
  const float w20 = wc[6], w21 = wc[7], w22 = wc[8];
  float ssq = 0.f;
#pragma unroll
  for (int nn = 0; nn < 2; ++nn) {
    float s[8];
#pragma unroll
    for (int j = 0; j < 8; ++j) {
      float v = a[nn][j] * w00;
      v = fmaf(a[nn][j + 1], w01, v);
      v = fmaf(a[nn][j + 2], w02, v);
      v = fmaf(a[nn + 1][j], w10, v);
      v = fmaf(a[nn + 1][j + 1], w11, v);
      v = fmaf(a[nn + 1][j + 2], w12, v);
      v = fmaf(a[nn + 2][j], w20, v);
      v = fmaf(a[nn + 2][j + 1], w21, v);
      v = fmaf(a[nn + 2][j + 2], w22, v);
      ssq = fmaf(v, v, ssq);
      s[j] = v;
    }
    *(uint4*)(out + ((size_t)bc << 14) + ((y0 + nn) << 7) + x0) =
        make_uint4(cvtpk(s[0], s[1]), cvtpk(s[2], s[3]), cvtpk(s[4], s[5]), cvtpk(s[6], s[7]));
  }

  if (c < 384) {
#pragma unroll
    for (int off = 32; off > 0; off >>= 1) ssq += __shfl_down(ssq, off, 64);
    if ((tid & 63) == 0) red[tid >> 6] = ssq;
    __syncthreads();
    if (tid == 0) {
      const int tt = (c < 192) ? mod : 2 + mod;
      atomicAdd(&norms2[(tt * NB + b) * NCH + (c % NCH)], red[0] + red[1] + red[2] + red[3]);
    }
  }
}

__global__ __launch_bounds__(256) void dwconv_kernel(
    const u16* __restrict__ in, const float* __restrict__ wdw, u16* __restrict__ out,
    float* __restrict__ norms2, const int mod) {
  __shared__ float red[4];
  dw_body(red, in, wdw, out, norms2, mod,
          (size_t)blockIdx.x * 256 + threadIdx.x, threadIdx.x);
}

// merged both modalities (needs distinct qkv2 buffer): 36864 blocks.
__global__ __launch_bounds__(256) void dwm_kernel(
    const u16* __restrict__ pre1, const float* __restrict__ wdw1, u16* __restrict__ qkv1,
    const u16* __restrict__ pre2, const float* __restrict__ wdw2, u16* __restrict__ qkv2,
    float* __restrict__ norms2) {
  __shared__ float red[4];
  const size_t t = (size_t)blockIdx.x * 256 + threadIdx.x;
  const int bc = (int)(t >> 10);              // [0, 9216)
  const int mod = (bc >= NB * NC3) ? 1 : 0;
  const size_t tm = t - ((size_t)mod * NB * NC3 << 10);
  if (mod)
    dw_body(red, pre2, wdw2, qkv2, norms2, 1, tm, threadIdx.x);
  else
    dw_body(red, pre1, wdw1, qkv1, norms2, 0, tm, threadIdx.x);
}

// ---------------------------------------------------------------------------
// Gram via MFMA, fragments direct from global (NT: contraction over n).
// In-block 4-wave reduce, then atomicAdd partial into G.
// ---------------------------------------------------------------------------
__global__ __launch_bounds__(256) void gram_mfma_kernel(
    const u16* __restrict__ qkv1, const u16* __restrict__ qkv2, float* __restrict__ G) {
  const int nc = blockIdx.x, h = blockIdx.y, b = blockIdx.z;
  const int tid = threadIdx.x;
  const int w = tid >> 6, l = tid & 63;

  const u16* qp[3];
  const u16* kp[3];
#pragma unroll
  for (int m = 0; m < 3; ++m) {
    const int rq = m * 16 + (l & 15);
    const int cc = h * 24 + (rq < 24 ? rq : rq - 24);
    const u16* basep = (rq < 24) ? qkv1 : qkv2;
    qp[m] = basep + (((size_t)b * NC3 + cc) << 14);
    kp[m] = basep + (((size_t)b * NC3 + 192 + cc) << 14);
  }
  const int kbase = nc * 1024 + w * 256 + (l >> 4) * 8;

  f32x4 acc[3][3];
#pragma unroll
  for (int m = 0; m < 3; ++m)
#pragma unroll
    for (int nf = 0; nf < 3; ++nf) acc[m][nf] = (f32x4)0.f;

  for (int t = 0; t < 8; ++t) {
    const int ko = kbase + t * 32;
    s16x8 a[3], bv[3];
#pragma unroll
    for (int m = 0; m < 3; ++m) {
      a[m] = *(const s16x8*)(qp[m] + ko);
      bv[m] = *(const s16x8*)(kp[m] + ko);
    }
#pragma unroll
    for (int m = 0; m < 3; ++m)
#pragma unroll
      for (int nf = 0; nf < 3; ++nf)
        acc[m][nf] = __builtin_amdgcn_mfma_f32_16x16x32_bf16(a[m], bv[nf], acc[m][nf], 0, 0, 0);
  }

  __shared__ float red[4][48][48];
#pragma unroll
  for (int m = 0; m < 3; ++m)
#pragma unroll
    for (int nf = 0; nf < 3; ++nf)
#pragma unroll
      for (int r = 0; r < 4; ++r)
        red[w][m * 16 + (l >> 4) * 4 + r][nf * 16 + (l & 15)] = acc[m][nf][r];
  __syncthreads();
  float* dst = G + ((size_t)b * 8 + h) * 2304;
  for (int e = tid; e < 2304; e += 256) {
    const int rr = e / 48, cc = e % 48;
    atomicAdd(&dst[e], red[0][rr][cc] + red[1][rr][cc] + red[2][rr][cc] + red[3][rr][cc]);
  }
}

// ---------------------------------------------------------------------------
// softmax (4x 24x24 per b,h) + fused weights, bf16 output
// ---------------------------------------------------------------------------
__global__ __launch_bounds__(256) void softmax_wcat_kernel(
    const float* __restrict__ G, const float* __restrict__ norms2,
    const float* __restrict__ temperature, const float* __restrict__ beta,
    const float* __restrict__ wproj, u16* __restrict__ Wcat) {
  const int bh = blockIdx.x;
  const int b = bh >> 3, h = bh & 7;
  __shared__ float sm[4][24][24];
  __shared__ float nrm[4][24];
  const int tid = threadIdx.x;
  if (tid < 96) {
    int t = tid / 24, ci = tid % 24;
    nrm[t][ci] = fmaxf(sqrtf(norms2[(t * NB + b) * NCH + h * 24 + ci]), 1e-12f);
  }
  __syncthreads();
  const float T = temperature[h];
  const float sigB = 1.f / (1.f + expf(-beta[0]));
  if (tid < 96) {
    const int m = tid / 24, r = tid % 24;
    const float* Gb = G + (size_t)bh * 2304;
    const int gr = (m >= 2) ? 24 + r : r;
    const int gc0 = (m == 1 || m == 2) ? 24 : 0;
    const float* qn = (m >= 2) ? nrm[1] : nrm[0];
    const float* kn = (m == 1 || m == 2) ? nrm[3] : nrm[2];
    const float sign = (m == 0 || m == 2) ? 1.f : -1.f;
    const float qs = sign * T / qn[r];
    float L[24], mx = -1e30f;
#pragma unroll
    for (int cc = 0; cc < 24; ++cc) {
      L[cc] = Gb[gr * 48 + gc0 + cc] * qs / kn[cc];
      mx = fmaxf(mx, L[cc]);
    }
    float ssum = 0.f;
#pragma unroll
    for (int cc = 0; cc < 24; ++cc) {
      L[cc] = expf(L[cc] - mx);
      ssum += L[cc];
    }
    const float inv = 1.f / ssum;
#pragma unroll
    for (int cc = 0; cc < 24; ++cc) sm[m][r][cc] = L[cc] * inv;
  }
  __syncthreads();
  for (int e = tid; e < 384 * 48; e += 256) {
    const int o = e / 48, dc = e % 48;
    const int part = dc / 24, d = dc % 24;
    const int oc = (o < 192) ? o : o - 192;
    int m;
    float scale;
    if (o < 192) { m = part ? 1 : 0; scale = part ? 1.f : sigB; }
    else         { m = part ? 2 : 3; scale = part ? sigB : 1.f; }
    float s = 0.f;
#pragma unroll
    for (int ci = 0; ci < 24; ++ci) s += wproj[oc * 192 + h * 24 + ci] * sm[m][ci][d];
    Wcat[((size_t)b * 384 + o) * 384 + part * 192 + h * 24 + d] = f2bf(s * scale);
  }
}

// ---------------------------------------------------------------------------
// final GEMM MFMA: A (Wcat, L2-resident) dbuf 2x16KB; B single 16KB write-late.
// LDS total 48KB. Non-temporal output stores.
// ---------------------------------------------------------------------------
__device__ __forceinline__ void fin_b_load(const u16* __restrict__ qkv1,
                                           const u16* __restrict__ qkv2,
                                           int b, int nbase, int kb, int w, int l,
                                           u32 (&val)[16]) {
  const u16* vbase = (kb < 192) ? qkv1 + (((size_t)b * NC3 + 384 + kb) << 14)
                                : qkv2 + (((size_t)b * NC3 + 384 + kb - 192) << 14);
  const u16* p0 = vbase + (((size_t)(w * 16)) << 14) + nbase + l * 2;
#pragma unroll
  for (int jj = 0; jj < 16; ++jj)
    val[jj] = *(const u32*)(p0 + ((size_t)jj << 14));
}

__device__ __forceinline__ void fin_b_write(char* smem, int w, int l,
                                            const u32 (&val)[16]) {
#pragma unroll
  for (int nn = 0; nn < 2; ++nn) {
    const int row = l * 2 + nn;
    u32 p[8];
#pragma unroll
    for (int q = 0; q < 8; ++q) {
      const u32 a = (val[2 * q] >> (nn * 16)) & 0xffffu;
      const u32 bb = (val[2 * q + 1] >> (nn * 16)) & 0xffffu;
      p[q] = a | (bb << 16);
    }
    char* base = smem + 32768 + row * 128;
    *(uint4*)(base + ((w * 32 + 0) ^ swz(row))) = make_uint4(p[0], p[1], p[2], p[3]);
    *(uint4*)(base + ((w * 32 + 16) ^ swz(row))) = make_uint4(p[4], p[5], p[6], p[7]);
  }
}

__device__ __forceinline__ void fin_a_glds(char* smem, const u16* __restrict__ Wcat,
                                           int b, int obase, int kb, int w, int l, int buf) {
#pragma unroll
  for (int i = 0; i < 4; ++i) {
    const int grp = i * 4 + w;
    const int row = grp * 8 + (l >> 3);
    const int cb = ((l & 7) * 16) ^ swz(row);
    const char* src = (const char*)Wcat + ((size_t)b * 384 + obase + row) * 768 + kb * 2 + cb;
    gl_lds16(src, smem + buf * 16384 + grp * 1024);
  }
}

__global__ __launch_bounds__(256) void final_mfma_kernel(
    const u16* __restrict__ qkv1, const u16* __restrict__ qkv2,
    const u16* __restrict__ Wcat, float* __restrict__ out) {
  __shared__ char smem[49152];
  const int bid = blockIdx.x;                      // 3072 blocks
  const int id = (bid & 7) * 384 + (bid >> 3);
  const int b = id / 384;
  const int rr2 = id % 384;
  const int nbase = (rr2 / 3) * 128;
  const int obase = (rr2 % 3) * 128;
  const int tid = threadIdx.x;
  const int w = tid >> 6, l = tid & 63;
  const int wr = w >> 1, wc = w & 1;

  f32x4 acc[4][4];
#pragma unroll
  for (int m = 0; m < 4; ++m)
#pragma unroll
    for (int nf = 0; nf < 4; ++nf) acc[m][nf] = (f32x4)0.f;

  u32 fV[16];
  fin_b_load(qkv1, qkv2, b, nbase, 0, w, l, fV);
  fin_a_glds(smem, Wcat, b, obase, 0, w, l, 0);
  fin_b_write(smem, w, l, fV);
  __syncthreads();

  for (int t = 0; t < 6; ++t) {
    const int cur = t & 1;
    const int nxt = cur ^ 1;
    if (t < 5) {
      fin_b_load(qkv1, qkv2, b, nbase, (t + 1) * 64, w, l, fV);  // issue early
      fin_a_glds(smem, Wcat, b, obase, (t + 1) * 64, w, l, nxt);
    }
#pragma unroll
    for (int kk = 0; kk < 2; ++kk) {
      s16x8 a[4], bv[4];
      const int cbk = kk * 64 + (l >> 4) * 16;
#pragma unroll
      for (int m = 0; m < 4; ++m) {
        const int rowA = wr * 64 + m * 16 + (l & 15);
        a[m] = *(const s16x8*)(smem + cur * 16384 + rowA * 128 + (cbk ^ swz(rowA)));
      }
#pragma unroll
      for (int nf = 0; nf < 4; ++nf) {
        const int rowB = wc * 64 + nf * 16 + (l & 15);
        bv[nf] = *(const s16x8*)(smem + 32768 + rowB * 128 + (cbk ^ swz(rowB)));
      }
#pragma unroll
      for (int m = 0; m < 4; ++m)
#pragma unroll
        for (int nf = 0; nf < 4; ++nf)
          acc[m][nf] = __builtin_amdgcn_mfma_f32_16x16x32_bf16(a[m], bv[nf], acc[m][nf], 0, 0, 0);
    }
    __syncthreads();               // all waves done reading B
    if (t < 5) {
      fin_b_write(smem, w, l, fV); // write late into the single B buffer
      __syncthreads();             // new B (and A[nxt]) ready
    }
  }
  // epilogue: per-wave LDS transpose ([16][68] f32), then nt float4 stores.
  float* cw = (float*)(smem + w * 4352);
#pragma unroll
  for (int m = 0; m < 4; ++m) {
#pragma unroll
    for (int nf = 0; nf < 4; ++nf)
#pragma unroll
      for (int r = 0; r < 4; ++r)
        cw[((l >> 4) * 4 + r) * 68 + nf * 16 + (l & 15)] = acc[m][nf][r];
#pragma unroll
    for (int p = 0; p < 4; ++p) {
      const int chunk = p * 64 + l;
      const int row = chunk >> 4, cg = chunk & 15;
      f32x4 v = *(const f32x4*)(cw + row * 68 + cg * 4);
      const int o = obase + wr * 64 + m * 16 + row;
      const int n = nbase + wc * 64 + cg * 4;
      float* dst = (o < 192) ? out + (((size_t)b * NCH + o) << 14) + n
                             : out + 25165824 + (((size_t)b * NCH + o - 192) << 14) + n;
      __builtin_nontemporal_store(v, (f32x4*)dst);
    }
  }
}

// ---------------------------------------------------------------------------
extern "C" void kernel_launch(void* const* d_in, const int* in_sizes, int n_in,
                              void* d_out, int out_size, void* d_ws, size_t ws_size,
                              hipStream_t stream) {
  (void)in_sizes; (void)n_in; (void)out_size;
  const float* x1 = (const float*)d_in[0];
  const float* x2 = (const float*)d_in[1];
  const float* w_qkv1 = (const float*)d_in[2];
  const float* w_dw1 = (const float*)d_in[3];
  const float* w_qkv2 = (const float*)d_in[4];
  const float* w_dw2 = (const float*)d_in[5];
  const float* w_proj = (const float*)d_in[6];
  const float* temperature = (const float*)d_in[7];
  const float* beta = (const float*)d_in[8];
  float* out = (float*)d_out;

  char* wsb = (char*)d_ws;
  const size_t BUF = 150994944;  // one 8x576x16384 bf16 plane set
  const bool big = ws_size >= 607395840;

  u16* pre1 = (u16*)(wsb);
  u16* qkv1 = (u16*)(wsb + BUF);
  u16* pre2 = (u16*)(wsb + 2 * BUF);
  u16* qkv2 = big ? (u16*)(wsb + 3 * BUF) : pre1;  // small ws: reuse pre1 after dw1
  char* tail = big ? (wsb + 4 * BUF) : (wsb + 3 * BUF);
  u16* wbf1 = (u16*)(tail);                 // 221,184
  u16* wbf2 = (u16*)(tail + 221184);        // 221,184
  float* norms2 = (float*)(tail + 442368);  // 24,576
  float* G = (float*)(tail + 466944);       // 589,824
  u16* WcatBf = (u16*)(tail + 1056768);     // 2,359,296 -> tail end 3,416,064

  const int dwblocks = (int)(((size_t)NB * NC3 * NHW) / (256 * 16));  // 18432

  wcast_kernel<<<576, 256, 0, stream>>>(w_qkv1, w_qkv2, wbf1, wbf2, norms2, G);
  conv_mfma_kernel<<<6144, 256, 0, stream>>>(x1, wbf1, pre1, x2, wbf2, pre2);
  if (big) {
    dwm_kernel<<<2 * dwblocks, 256, 0, stream>>>(pre1, w_dw1, qkv1, pre2, w_dw2, qkv2, norms2);
  } else {
    dwconv_kernel<<<dwblocks, 256, 0, stream>>>(pre1, w_dw1, qkv1, norms2, 0);
    dwconv_kernel<<<dwblocks, 256, 0, stream>>>(pre2, w_dw2, qkv2, norms2, 1);
  }
  gram_mfma_kernel<<<dim3(16, NHEADS, NB), 256, 0, stream>>>(qkv1, qkv2, G);
  softmax_wcat_kernel<<<NB * NHEADS, 256, 0, stream>>>(G, norms2, temperature, beta, w_proj, WcatBf);
  final_mfma_kernel<<<3072, 256, 0, stream>>>(qkv1, qkv2, WcatBf, out);
}

// Round 16
// 450.859 us; speedup vs baseline: 1.0945x; 1.0945x over previous
//
#include <hip/hip_runtime.h>

typedef unsigned short u16;
typedef unsigned int u32;

#define NB 8
#define NCH 192
#define NC3 576
#define NHW 16384
#define NHEADS 8

typedef __attribute__((ext_vector_type(8))) short s16x8;
typedef __attribute__((ext_vector_type(4))) float f32x4;

__device__ __forceinline__ float bf2f(u32 h) {
  return __uint_as_float(h << 16);
}
__device__ __forceinline__ u16 f2bf(float f) {
  u32 u = __float_as_uint(f);
  u = (u + 0x7fffu + ((u >> 16) & 1u)) >> 16;
  return (u16)u;
}
__device__ __forceinline__ u32 pk2(u16 a, u16 b) { return (u32)a | ((u32)b << 16); }

// XOR swizzle within a 128-byte LDS row.
__device__ __forceinline__ int swz(int row) { return ((row >> 1) & 7) << 4; }

__device__ __forceinline__ void gl_lds16(const void* g, void* s) {
  __builtin_amdgcn_global_load_lds((const __attribute__((address_space(1))) unsigned int*)g,
                                   (__attribute__((address_space(3))) unsigned int*)s, 16, 0, 0);
}

// ---------------------------------------------------------------------------
// cast conv weights fp32 -> bf16; zero norms2 and G accumulators
// ---------------------------------------------------------------------------
__global__ __launch_bounds__(256) void wcast_kernel(
    const float* __restrict__ w1, const float* __restrict__ w2,
    u16* __restrict__ o1, u16* __restrict__ o2, float* __restrict__ norms2,
    float* __restrict__ G) {
  int i = blockIdx.x * 256 + threadIdx.x;
  if (i < NC3 * NCH) {
    o1[i] = f2bf(w1[i]);
    o2[i] = f2bf(w2[i]);
  }
  if (i < 4 * NB * NCH) norms2[i] = 0.f;
  if (i < NB * NHEADS * 2304) G[i] = 0.f;
}

// ---------------------------------------------------------------------------
// conv1x1 MFMA, MERGED both modalities: 6144 blocks, modality from block id.
// 40KB LDS (A single 24KB via gl_lds @0, B single 16KB @24576) -> 4 blocks/CU.
// Per K-step: a_glds(t); b_write(t); b_load(t+1); barrier; MFMA(t); barrier.
// ---------------------------------------------------------------------------
__device__ __forceinline__ void conv_b_load(const float* __restrict__ x, int b, int nbase,
                                            int kb, int w, int l, float2 (&val)[16]) {
  const float* xr = x + (((size_t)(b * NCH + kb + w * 16)) << 14) + nbase + l * 2;
#pragma unroll
  for (int jj = 0; jj < 16; ++jj)
    val[jj] = *(const float2*)(xr + ((size_t)jj << 14));
}

__device__ __forceinline__ void conv_b_write(char* smem, int w, int l,
                                             const float2 (&val)[16]) {
#pragma unroll
  for (int nn = 0; nn < 2; ++nn) {
    const int row = l * 2 + nn;
    u32 p[8];
#pragma unroll
    for (int q = 0; q < 8; ++q) {
      const float a = nn ? val[2 * q].y : val[2 * q].x;
      const float bb = nn ? val[2 * q + 1].y : val[2 * q + 1].x;
      p[q] = pk2(f2bf(a), f2bf(bb));
    }
    char* base = smem + 24576 + row * 128;
    *(uint4*)(base + ((w * 32 + 0) ^ swz(row))) = make_uint4(p[0], p[1], p[2], p[3]);
    *(uint4*)(base + ((w * 32 + 16) ^ swz(row))) = make_uint4(p[4], p[5], p[6], p[7]);
  }
}

__device__ __forceinline__ void conv_a_glds(char* smem, const u16* __restrict__ wbf,
                                            int obase, int kb, int w, int l) {
#pragma unroll
  for (int i = 0; i < 6; ++i) {
    const int grp = i * 4 + w;
    const int row = grp * 8 + (l >> 3);
    const int cb = ((l & 7) * 16) ^ swz(row);
    const char* src = (const char*)wbf + (size_t)(obase + row) * 384 + kb * 2 + cb;
    gl_lds16(src, smem + grp * 1024);
  }
}

__global__ __launch_bounds__(256) void conv_mfma_kernel(
    const float* __restrict__ x1, const u16* __restrict__ wbf1, u16* __restrict__ pre1,
    const float* __restrict__ x2, const u16* __restrict__ wbf2, u16* __restrict__ pre2) {
  __shared__ char smem[40960];
  const int bid = blockIdx.x;                      // 6144 blocks
  const int id = (bid & 7) * 768 + (bid >> 3);     // bijective XCD chunk
  const int mod = (id >= 3072) ? 1 : 0;
  const int idm = id - mod * 3072;
  const float* x = mod ? x2 : x1;
  const u16* wbf = mod ? wbf2 : wbf1;
  u16* pre = mod ? pre2 : pre1;
  const int b = idm / 384;
  const int rr = idm % 384;
  const int nbase = (rr / 3) * 128;
  const int obase = (rr % 3) * 192;
  const int tid = threadIdx.x;
  const int w = tid >> 6, l = tid & 63;
  const int wr = w >> 1, wc = w & 1;

  f32x4 acc[6][4];
#pragma unroll
  for (int m = 0; m < 6; ++m)
#pragma unroll
    for (int nf = 0; nf < 4; ++nf) acc[m][nf] = (f32x4)0.f;

  float2 fB[16];
  conv_b_load(x, b, nbase, 0, w, l, fB);

  for (int t = 0; t < 3; ++t) {
    conv_a_glds(smem, wbf, obase, t * 64, w, l);
    conv_b_write(smem, w, l, fB);
    if (t < 2) conv_b_load(x, b, nbase, (t + 1) * 64, w, l, fB);  // issue early
    __syncthreads();  // A(t), B(t) resident
#pragma unroll
    for (int kk = 0; kk < 2; ++kk) {
      s16x8 a[6], bv[4];
      const int cbk = kk * 64 + (l >> 4) * 16;
#pragma unroll
      for (int m = 0; m < 6; ++m) {
        const int rowA = wr * 96 + m * 16 + (l & 15);
        a[m] = *(const s16x8*)(smem + rowA * 128 + (cbk ^ swz(rowA)));
      }
#pragma unroll
      for (int nf = 0; nf < 4; ++nf) {
        const int rowB = wc * 64 + nf * 16 + (l & 15);
        bv[nf] = *(const s16x8*)(smem + 24576 + rowB * 128 + (cbk ^ swz(rowB)));
      }
#pragma unroll
      for (int m = 0; m < 6; ++m)
#pragma unroll
        for (int nf = 0; nf < 4; ++nf)
          acc[m][nf] = __builtin_amdgcn_mfma_f32_16x16x32_bf16(a[m], bv[nf], acc[m][nf], 0, 0, 0);
    }
    __syncthreads();  // all waves done reading before next overwrite
  }
  // epilogue: per-wave LDS transpose ([16][72] u16), then 16B stores.
  u16* cw = (u16*)(smem) + w * 16 * 72;
#pragma unroll
  for (int m = 0; m < 6; ++m) {
#pragma unroll
    for (int nf = 0; nf < 4; ++nf)
#pragma unroll
      for (int r = 0; r < 4; ++r)
        cw[((l >> 4) * 4 + r) * 72 + nf * 16 + (l & 15)] = f2bf(acc[m][nf][r]);
#pragma unroll
    for (int p = 0; p < 2; ++p) {
      const int chunk = p * 64 + l;
      const int row = chunk >> 3, cg = chunk & 7;
      uint4 v = *(const uint4*)(cw + row * 72 + cg * 8);
      const int o = obase + wr * 96 + m * 16 + row;
      const int n = nbase + wc * 64 + cg * 8;
      *(uint4*)(pre + (((size_t)b * NC3 + o) << 14) + n) = v;
    }
  }
}

// ---------------------------------------------------------------------------
// depthwise 3x3, 2 output rows x 8 px per thread (halo amp 3x -> 2x)
// + fused sum-of-squares for q,k planes.
// ---------------------------------------------------------------------------
__device__ __forceinline__ void dw_body(float* red, const u16* __restrict__ in,
                                        const float* __restrict__ wdw, u16* __restrict__ out,
                                        float* __restrict__ norms2, const int mod,
                                        const size_t t, const int tid) {
  const int l = tid & 63;
  const int xc = (int)(t & 15);
  const int yp = (int)((t >> 4) & 63);
  const int bc = (int)(t >> 10);
  const int c = bc % NC3;
  const int b = bc / NC3;
  const u16* p = in + ((size_t)bc << 14);
  const float* wc = wdw + c * 9;
  const int x0 = xc * 8;
  const int y0 = yp * 2;

  float a[4][10];
#pragma unroll
  for (int r = 0; r < 4; ++r) {
    const int y2 = y0 + r - 1;
    if ((unsigned)y2 < 128u) {
      const u16* row = p + (y2 << 7);
      uint4 v = *(const uint4*)(row + x0);
      a[r][1] = bf2f(v.x & 0xffff); a[r][2] = bf2f(v.x >> 16);
      a[r][3] = bf2f(v.y & 0xffff); a[r][4] = bf2f(v.y >> 16);
      a[r][5] = bf2f(v.z & 0xffff); a[r][6] = bf2f(v.z >> 16);
      a[r][7] = bf2f(v.w & 0xffff); a[r][8] = bf2f(v.w >> 16);
    } else {
#pragma unroll
      for (int j = 1; j < 9; ++j) a[r][j] = 0.f;
    }
    const float lf = __shfl(a[r][8], (l - 1) & 63, 64);
    const float rt = __shfl(a[r][1], (l + 1) & 63, 64);
    a[r][0] = (xc > 0) ? lf : 0.f;
    a[r][9] = (xc < 15) ? rt : 0.f;
  }
  const float w00 = wc[0], w01 = wc[1], w02 = wc[2];
  const float w10 = wc[3], w11 = wc[4], w12 = wc[5];
  const float w20 = wc[6], w21 = wc[7], w22 = wc[8];
  float ssq = 0.f;
#pragma unroll
  for (int nn = 0; nn < 2; ++nn) {
    u16 o[8];
#pragma unroll
    for (int j = 0; j < 8; ++j) {
      float s = a[nn][j] * w00;
      s = fmaf(a[nn][j + 1], w01, s);
      s = fmaf(a[nn][j + 2], w02, s);
      s = fmaf(a[nn + 1][j], w10, s);
      s = fmaf(a[nn + 1][j + 1], w11, s);
      s = fmaf(a[nn + 1][j + 2], w12, s);
      s = fmaf(a[nn + 2][j], w20, s);
      s = fmaf(a[nn + 2][j + 1], w21, s);
      s = fmaf(a[nn + 2][j + 2], w22, s);
      ssq = fmaf(s, s, ssq);
      o[j] = f2bf(s);
    }
    *(uint4*)(out + ((size_t)bc << 14) + ((y0 + nn) << 7) + x0) =
        make_uint4(pk2(o[0], o[1]), pk2(o[2], o[3]), pk2(o[4], o[5]), pk2(o[6], o[7]));
  }

  if (c < 384) {
#pragma unroll
    for (int off = 32; off > 0; off >>= 1) ssq += __shfl_down(ssq, off, 64);
    if ((tid & 63) == 0) red[tid >> 6] = ssq;
    __syncthreads();
    if (tid == 0) {
      const int tt = (c < 192) ? mod : 2 + mod;
      atomicAdd(&norms2[(tt * NB + b) * NCH + (c % NCH)], red[0] + red[1] + red[2] + red[3]);
    }
  }
}

__global__ __launch_bounds__(256) void dwconv_kernel(
    const u16* __restrict__ in, const float* __restrict__ wdw, u16* __restrict__ out,
    float* __restrict__ norms2, const int mod) {
  __shared__ float red[4];
  dw_body(red, in, wdw, out, norms2, mod,
          (size_t)blockIdx.x * 256 + threadIdx.x, threadIdx.x);
}

// merged both modalities (needs distinct qkv2 buffer): 36864 blocks.
__global__ __launch_bounds__(256) void dwm_kernel(
    const u16* __restrict__ pre1, const float* __restrict__ wdw1, u16* __restrict__ qkv1,
    const u16* __restrict__ pre2, const float* __restrict__ wdw2, u16* __restrict__ qkv2,
    float* __restrict__ norms2) {
  __shared__ float red[4];
  const size_t t = (size_t)blockIdx.x * 256 + threadIdx.x;
  const int bc = (int)(t >> 10);              // [0, 9216)
  const int mod = (bc >= NB * NC3) ? 1 : 0;
  const size_t tm = t - ((size_t)mod * NB * NC3 << 10);
  if (mod)
    dw_body(red, pre2, wdw2, qkv2, norms2, 1, tm, threadIdx.x);
  else
    dw_body(red, pre1, wdw1, qkv1, norms2, 0, tm, threadIdx.x);
}

// ---------------------------------------------------------------------------
// Gram via MFMA, fragments direct from global (NT: contraction over n).
// In-block 4-wave reduce, then atomicAdd partial into G.
// ---------------------------------------------------------------------------
__global__ __launch_bounds__(256) void gram_mfma_kernel(
    const u16* __restrict__ qkv1, const u16* __restrict__ qkv2, float* __restrict__ G) {
  const int nc = blockIdx.x, h = blockIdx.y, b = blockIdx.z;
  const int tid = threadIdx.x;
  const int w = tid >> 6, l = tid & 63;

  const u16* qp[3];
  const u16* kp[3];
#pragma unroll
  for (int m = 0; m < 3; ++m) {
    const int rq = m * 16 + (l & 15);
    const int cc = h * 24 + (rq < 24 ? rq : rq - 24);
    const u16* basep = (rq < 24) ? qkv1 : qkv2;
    qp[m] = basep + (((size_t)b * NC3 + cc) << 14);
    kp[m] = basep + (((size_t)b * NC3 + 192 + cc) << 14);
  }
  const int kbase = nc * 1024 + w * 256 + (l >> 4) * 8;

  f32x4 acc[3][3];
#pragma unroll
  for (int m = 0; m < 3; ++m)
#pragma unroll
    for (int nf = 0; nf < 3; ++nf) acc[m][nf] = (f32x4)0.f;

  for (int t = 0; t < 8; ++t) {
    const int ko = kbase + t * 32;
    s16x8 a[3], bv[3];
#pragma unroll
    for (int m = 0; m < 3; ++m) {
      a[m] = *(const s16x8*)(qp[m] + ko);
      bv[m] = *(const s16x8*)(kp[m] + ko);
    }
#pragma unroll
    for (int m = 0; m < 3; ++m)
#pragma unroll
      for (int nf = 0; nf < 3; ++nf)
        acc[m][nf] = __builtin_amdgcn_mfma_f32_16x16x32_bf16(a[m], bv[nf], acc[m][nf], 0, 0, 0);
  }

  __shared__ float red[4][48][48];
#pragma unroll
  for (int m = 0; m < 3; ++m)
#pragma unroll
    for (int nf = 0; nf < 3; ++nf)
#pragma unroll
      for (int r = 0; r < 4; ++r)
        red[w][m * 16 + (l >> 4) * 4 + r][nf * 16 + (l & 15)] = acc[m][nf][r];
  __syncthreads();
  float* dst = G + ((size_t)b * 8 + h) * 2304;
  for (int e = tid; e < 2304; e += 256) {
    const int rr = e / 48, cc = e % 48;
    atomicAdd(&dst[e], red[0][rr][cc] + red[1][rr][cc] + red[2][rr][cc] + red[3][rr][cc]);
  }
}

// ---------------------------------------------------------------------------
// softmax (4x 24x24 per b,h) + fused weights, bf16 output
// ---------------------------------------------------------------------------
__global__ __launch_bounds__(256) void softmax_wcat_kernel(
    const float* __restrict__ G, const float* __restrict__ norms2,
    const float* __restrict__ temperature, const float* __restrict__ beta,
    const float* __restrict__ wproj, u16* __restrict__ Wcat) {
  const int bh = blockIdx.x;
  const int b = bh >> 3, h = bh & 7;
  __shared__ float sm[4][24][24];
  __shared__ float nrm[4][24];
  const int tid = threadIdx.x;
  if (tid < 96) {
    int t = tid / 24, ci = tid % 24;
    nrm[t][ci] = fmaxf(sqrtf(norms2[(t * NB + b) * NCH + h * 24 + ci]), 1e-12f);
  }
  __syncthreads();
  const float T = temperature[h];
  const float sigB = 1.f / (1.f + expf(-beta[0]));
  if (tid < 96) {
    const int m = tid / 24, r = tid % 24;
    const float* Gb = G + (size_t)bh * 2304;
    const int gr = (m >= 2) ? 24 + r : r;
    const int gc0 = (m == 1 || m == 2) ? 24 : 0;
    const float* qn = (m >= 2) ? nrm[1] : nrm[0];
    const float* kn = (m == 1 || m == 2) ? nrm[3] : nrm[2];
    const float sign = (m == 0 || m == 2) ? 1.f : -1.f;
    const float qs = sign * T / qn[r];
    float L[24], mx = -1e30f;
#pragma unroll
    for (int cc = 0; cc < 24; ++cc) {
      L[cc] = Gb[gr * 48 + gc0 + cc] * qs / kn[cc];
      mx = fmaxf(mx, L[cc]);
    }
    float ssum = 0.f;
#pragma unroll
    for (int cc = 0; cc < 24; ++cc) {
      L[cc] = expf(L[cc] - mx);
      ssum += L[cc];
    }
    const float inv = 1.f / ssum;
#pragma unroll
    for (int cc = 0; cc < 24; ++cc) sm[m][r][cc] = L[cc] * inv;
  }
  __syncthreads();
  for (int e = tid; e < 384 * 48; e += 256) {
    const int o = e / 48, dc = e % 48;
    const int part = dc / 24, d = dc % 24;
    const int oc = (o < 192) ? o : o - 192;
    int m;
    float scale;
    if (o < 192) { m = part ? 1 : 0; scale = part ? 1.f : sigB; }
    else         { m = part ? 2 : 3; scale = part ? sigB : 1.f; }
    float s = 0.f;
#pragma unroll
    for (int ci = 0; ci < 24; ++ci) s += wproj[oc * 192 + h * 24 + ci] * sm[m][ci][d];
    Wcat[((size_t)b * 384 + o) * 384 + part * 192 + h * 24 + d] = f2bf(s * scale);
  }
}

// ---------------------------------------------------------------------------
// final GEMM MFMA: A (Wcat, L2-resident) dbuf 2x16KB; B single 16KB write-late.
// LDS total 48KB -> 3 blocks/CU. Non-temporal output stores.
// ---------------------------------------------------------------------------
__device__ __forceinline__ void fin_b_load(const u16* __restrict__ qkv1,
                                           const u16* __restrict__ qkv2,
                                           int b, int nbase, int kb, int w, int l,
                                           u32 (&val)[16]) {
  const u16* vbase = (kb < 192) ? qkv1 + (((size_t)b * NC3 + 384 + kb) << 14)
                                : qkv2 + (((size_t)b * NC3 + 384 + kb - 192) << 14);
  const u16* p0 = vbase + (((size_t)(w * 16)) << 14) + nbase + l * 2;
#pragma unroll
  for (int jj = 0; jj < 16; ++jj)
    val[jj] = *(const u32*)(p0 + ((size_t)jj << 14));
}

__device__ __forceinline__ void fin_b_write(char* smem, int w, int l,
                                            const u32 (&val)[16]) {
#pragma unroll
  for (int nn = 0; nn < 2; ++nn) {
    const int row = l * 2 + nn;
    u32 p[8];
#pragma unroll
    for (int q = 0; q < 8; ++q) {
      const u32 a = (val[2 * q] >> (nn * 16)) & 0xffffu;
      const u32 bb = (val[2 * q + 1] >> (nn * 16)) & 0xffffu;
      p[q] = a | (bb << 16);
    }
    char* base = smem + 32768 + row * 128;
    *(uint4*)(base + ((w * 32 + 0) ^ swz(row))) = make_uint4(p[0], p[1], p[2], p[3]);
    *(uint4*)(base + ((w * 32 + 16) ^ swz(row))) = make_uint4(p[4], p[5], p[6], p[7]);
  }
}

__device__ __forceinline__ void fin_a_glds(char* smem, const u16* __restrict__ Wcat,
                                           int b, int obase, int kb, int w, int l, int buf) {
#pragma unroll
  for (int i = 0; i < 4; ++i) {
    const int grp = i * 4 + w;
    const int row = grp * 8 + (l >> 3);
    const int cb = ((l & 7) * 16) ^ swz(row);
    const char* src = (const char*)Wcat + ((size_t)b * 384 + obase + row) * 768 + kb * 2 + cb;
    gl_lds16(src, smem + buf * 16384 + grp * 1024);
  }
}

__global__ __launch_bounds__(256) void final_mfma_kernel(
    const u16* __restrict__ qkv1, const u16* __restrict__ qkv2,
    const u16* __restrict__ Wcat, float* __restrict__ out) {
  __shared__ char smem[49152];
  const int bid = blockIdx.x;                      // 3072 blocks
  const int id = (bid & 7) * 384 + (bid >> 3);
  const int b = id / 384;
  const int rr2 = id % 384;
  const int nbase = (rr2 / 3) * 128;
  const int obase = (rr2 % 3) * 128;
  const int tid = threadIdx.x;
  const int w = tid >> 6, l = tid & 63;
  const int wr = w >> 1, wc = w & 1;

  f32x4 acc[4][4];
#pragma unroll
  for (int m = 0; m < 4; ++m)
#pragma unroll
    for (int nf = 0; nf < 4; ++nf) acc[m][nf] = (f32x4)0.f;

  u32 fV[16];
  fin_b_load(qkv1, qkv2, b, nbase, 0, w, l, fV);
  fin_a_glds(smem, Wcat, b, obase, 0, w, l, 0);
  fin_b_write(smem, w, l, fV);
  __syncthreads();

  for (int t = 0; t < 6; ++t) {
    const int cur = t & 1;
    const int nxt = cur ^ 1;
    if (t < 5) {
      fin_b_load(qkv1, qkv2, b, nbase, (t + 1) * 64, w, l, fV);  // issue early
      fin_a_glds(smem, Wcat, b, obase, (t + 1) * 64, w, l, nxt);
    }
#pragma unroll
    for (int kk = 0; kk < 2; ++kk) {
      s16x8 a[4], bv[4];
      const int cbk = kk * 64 + (l >> 4) * 16;
#pragma unroll
      for (int m = 0; m < 4; ++m) {
        const int rowA = wr * 64 + m * 16 + (l & 15);
        a[m] = *(const s16x8*)(smem + cur * 16384 + rowA * 128 + (cbk ^ swz(rowA)));
      }
#pragma unroll
      for (int nf = 0; nf < 4; ++nf) {
        const int rowB = wc * 64 + nf * 16 + (l & 15);
        bv[nf] = *(const s16x8*)(smem + 32768 + rowB * 128 + (cbk ^ swz(rowB)));
      }
#pragma unroll
      for (int m = 0; m < 4; ++m)
#pragma unroll
        for (int nf = 0; nf < 4; ++nf)
          acc[m][nf] = __builtin_amdgcn_mfma_f32_16x16x32_bf16(a[m], bv[nf], acc[m][nf], 0, 0, 0);
    }
    __syncthreads();               // all waves done reading B
    if (t < 5) {
      fin_b_write(smem, w, l, fV); // write late into the single B buffer
      __syncthreads();             // new B (and A[nxt]) ready
    }
  }
  // epilogue: per-wave LDS transpose ([16][68] f32), then nt float4 stores.
  float* cw = (float*)(smem + w * 4352);
#pragma unroll
  for (int m = 0; m < 4; ++m) {
#pragma unroll
    for (int nf = 0; nf < 4; ++nf)
#pragma unroll
      for (int r = 0; r < 4; ++r)
        cw[((l >> 4) * 4 + r) * 68 + nf * 16 + (l & 15)] = acc[m][nf][r];
#pragma unroll
    for (int p = 0; p < 4; ++p) {
      const int chunk = p * 64 + l;
      const int row = chunk >> 4, cg = chunk & 15;
      f32x4 v = *(const f32x4*)(cw + row * 68 + cg * 4);
      const int o = obase + wr * 64 + m * 16 + row;
      const int n = nbase + wc * 64 + cg * 4;
      float* dst = (o < 192) ? out + (((size_t)b * NCH + o) << 14) + n
                             : out + 25165824 + (((size_t)b * NCH + o - 192) << 14) + n;
      __builtin_nontemporal_store(v, (f32x4*)dst);
    }
  }
}

// ---------------------------------------------------------------------------
extern "C" void kernel_launch(void* const* d_in, const int* in_sizes, int n_in,
                              void* d_out, int out_size, void* d_ws, size_t ws_size,
                              hipStream_t stream) {
  (void)in_sizes; (void)n_in; (void)out_size;
  const float* x1 = (const float*)d_in[0];
  const float* x2 = (const float*)d_in[1];
  const float* w_qkv1 = (const float*)d_in[2];
  const float* w_dw1 = (const float*)d_in[3];
  const float* w_qkv2 = (const float*)d_in[4];
  const float* w_dw2 = (const float*)d_in[5];
  const float* w_proj = (const float*)d_in[6];
  const float* temperature = (const float*)d_in[7];
  const float* beta = (const float*)d_in[8];
  float* out = (float*)d_out;

  char* wsb = (char*)d_ws;
  const size_t BUF = 150994944;  // one 8x576x16384 bf16 plane set
  const bool big = ws_size >= 607395840;

  u16* pre1 = (u16*)(wsb);
  u16* qkv1 = (u16*)(wsb + BUF);
  u16* pre2 = (u16*)(wsb + 2 * BUF);
  u16* qkv2 = big ? (u16*)(wsb + 3 * BUF) : pre1;  // small ws: reuse pre1 after dw1
  char* tail = big ? (wsb + 4 * BUF) : (wsb + 3 * BUF);
  u16* wbf1 = (u16*)(tail);                 // 221,184
  u16* wbf2 = (u16*)(tail + 221184);        // 221,184
  float* norms2 = (float*)(tail + 442368);  // 24,576
  float* G = (float*)(tail + 466944);       // 589,824
  u16* WcatBf = (u16*)(tail + 1056768);     // 2,359,296 -> tail end 3,416,064

  const int dwblocks = (int)(((size_t)NB * NC3 * NHW) / (256 * 16));  // 18432

  wcast_kernel<<<576, 256, 0, stream>>>(w_qkv1, w_qkv2, wbf1, wbf2, norms2, G);
  conv_mfma_kernel<<<6144, 256, 0, stream>>>(x1, wbf1, pre1, x2, wbf2, pre2);
  if (big) {
    dwm_kernel<<<2 * dwblocks, 256, 0, stream>>>(pre1, w_dw1, qkv1, pre2, w_dw2, qkv2, norms2);
  } else {
    dwconv_kernel<<<dwblocks, 256, 0, stream>>>(pre1, w_dw1, qkv1, norms2, 0);
    dwconv_kernel<<<dwblocks, 256, 0, stream>>>(pre2, w_dw2, qkv2, norms2, 1);
  }
  gram_mfma_kernel<<<dim3(16, NHEADS, NB), 256, 0, stream>>>(qkv1, qkv2, G);
  softmax_wcat_kernel<<<NB * NHEADS, 256, 0, stream>>>(G, norms2, temperature, beta, w_proj, WcatBf);
  final_mfma_kernel<<<3072, 256, 0, stream>>>(qkv1, qkv2, WcatBf, out);
}

// Round 17
// 427.630 us; speedup vs baseline: 1.1540x; 1.0543x over previous
//
#include <hip/hip_runtime.h>

typedef unsigned short u16;
typedef unsigned int u32;

#define NB 8
#define NCH 192
#define NC3 576
#define NHW 16384
#define NHEADS 8

typedef __attribute__((ext_vector_type(8))) short s16x8;
typedef __attribute__((ext_vector_type(4))) float f32x4;

__device__ __forceinline__ float bf2f(u32 h) {
  return __uint_as_float(h << 16);
}
__device__ __forceinline__ u16 f2bf(float f) {
  u32 u = __float_as_uint(f);
  u = (u + 0x7fffu + ((u >> 16) & 1u)) >> 16;
  return (u16)u;
}
__device__ __forceinline__ u32 pk2(u16 a, u16 b) { return (u32)a | ((u32)b << 16); }

// XOR swizzle within a 128-byte LDS row.
__device__ __forceinline__ int swz(int row) { return ((row >> 1) & 7) << 4; }

__device__ __forceinline__ void gl_lds16(const void* g, void* s) {
  __builtin_amdgcn_global_load_lds((const __attribute__((address_space(1))) unsigned int*)g,
                                   (__attribute__((address_space(3))) unsigned int*)s, 16, 0, 0);
}

// ---------------------------------------------------------------------------
// cast conv weights fp32 -> bf16; zero norms2 and G accumulators
// ---------------------------------------------------------------------------
__global__ __launch_bounds__(256) void wcast_kernel(
    const float* __restrict__ w1, const float* __restrict__ w2,
    u16* __restrict__ o1, u16* __restrict__ o2, float* __restrict__ norms2,
    float* __restrict__ G) {
  int i = blockIdx.x * 256 + threadIdx.x;
  if (i < NC3 * NCH) {
    o1[i] = f2bf(w1[i]);
    o2[i] = f2bf(w2[i]);
  }
  if (i < 4 * NB * NCH) norms2[i] = 0.f;
  if (i < NB * NHEADS * 2304) G[i] = 0.f;
}

// ---------------------------------------------------------------------------
// conv1x1 MFMA, B-resident: each block owns one (mod,b,64-wide n-tile),
// stages B = x[n][k] (full K=192, 24 KB, swizzled) ONCE, then loops all
// 3 o-tiles x 3 K-steps streaming A (24 KB via gl_lds, L2-resident weights).
// LDS: B @0 (24576), A @24576 (24576) = 48 KB -> 3 blocks/CU.
// HBM x latency is prologue-only; loop barriers drain only weight gl_lds.
// ---------------------------------------------------------------------------
__global__ __launch_bounds__(256) void conv_mfma_kernel(
    const float* __restrict__ x1, const u16* __restrict__ wbf1, u16* __restrict__ pre1,
    const float* __restrict__ x2, const u16* __restrict__ wbf2, u16* __restrict__ pre2) {
  __shared__ char smem[49152];
  const int bid = blockIdx.x;                      // 4096 blocks
  const int id = (bid & 7) * 512 + (bid >> 3);     // bijective XCD chunk
  const int mod = (id >= 2048) ? 1 : 0;
  const int idm = id - mod * 2048;
  const float* x = mod ? x2 : x1;
  const u16* wbf = mod ? wbf2 : wbf1;
  u16* pre = mod ? pre2 : pre1;
  const int b = idm >> 8;
  const int nbase = (idm & 255) * 64;
  const int tid = threadIdx.x;
  const int w = tid >> 6, l = tid & 63;

  // ---- prologue: stage B once. thread: row (n) = l, k-chunk = [w*48, w*48+48)
  {
    const int row = l;
    const int k0 = w * 48;
    float v[48];
#pragma unroll
    for (int j = 0; j < 48; ++j)
      v[j] = x[(((size_t)(b * NCH + k0 + j)) << 14) + nbase + row];
    char* base = smem + row * 384;
    const int sw = (row & 7) << 4;
#pragma unroll
    for (int q = 0; q < 6; ++q) {
      uint4 pv = make_uint4(pk2(f2bf(v[q * 8 + 0]), f2bf(v[q * 8 + 1])),
                            pk2(f2bf(v[q * 8 + 2]), f2bf(v[q * 8 + 3])),
                            pk2(f2bf(v[q * 8 + 4]), f2bf(v[q * 8 + 5])),
                            pk2(f2bf(v[q * 8 + 6]), f2bf(v[q * 8 + 7])));
      *(uint4*)(base + ((w * 96 + q * 16) ^ sw)) = pv;
    }
  }

  for (int ot = 0; ot < 3; ++ot) {
    const int obase = ot * 192;
    f32x4 acc[3][4];
#pragma unroll
    for (int m = 0; m < 3; ++m)
#pragma unroll
      for (int nf = 0; nf < 4; ++nf) acc[m][nf] = (f32x4)0.f;

    for (int kt = 0; kt < 3; ++kt) {
      // A stage: [192][64] bf16, 128-B rows, swizzled; 24 groups of 1 KB.
#pragma unroll
      for (int i = 0; i < 6; ++i) {
        const int grp = i * 4 + w;
        const int row = grp * 8 + (l >> 3);
        const int cb = ((l & 7) * 16) ^ swz(row);
        const char* src = (const char*)wbf + (size_t)(obase + row) * 384 + kt * 128 + cb;
        gl_lds16(src, smem + 24576 + grp * 1024);
      }
      __syncthreads();  // A(kt) resident (B already resident from prologue)
#pragma unroll
      for (int kk = 0; kk < 2; ++kk) {
        s16x8 a[3], bv[4];
        const int cbkA = kk * 64 + (l >> 4) * 16;
#pragma unroll
        for (int m = 0; m < 3; ++m) {
          const int rowA = w * 48 + m * 16 + (l & 15);
          a[m] = *(const s16x8*)(smem + 24576 + rowA * 128 + (cbkA ^ swz(rowA)));
        }
        const int kOff = kt * 128 + kk * 64 + (l >> 4) * 16;
#pragma unroll
        for (int nf = 0; nf < 4; ++nf) {
          const int rowB = nf * 16 + (l & 15);
          bv[nf] = *(const s16x8*)(smem + rowB * 384 + (kOff ^ ((rowB & 7) << 4)));
        }
#pragma unroll
        for (int m = 0; m < 3; ++m)
#pragma unroll
          for (int nf = 0; nf < 4; ++nf)
            acc[m][nf] = __builtin_amdgcn_mfma_f32_16x16x32_bf16(a[m], bv[nf], acc[m][nf], 0, 0, 0);
      }
      __syncthreads();  // all waves done reading A before next overwrite
    }
    // epilogue(ot): per-wave LDS transpose in (dead) A region, 16B stores.
    u16* cw = (u16*)(smem + 24576) + w * 1152;  // [16][72] u16 per wave
#pragma unroll
    for (int m = 0; m < 3; ++m) {
#pragma unroll
      for (int nf = 0; nf < 4; ++nf)
#pragma unroll
        for (int r = 0; r < 4; ++r)
          cw[((l >> 4) * 4 + r) * 72 + nf * 16 + (l & 15)] = f2bf(acc[m][nf][r]);
#pragma unroll
      for (int p = 0; p < 2; ++p) {
        const int chunk = p * 64 + l;
        const int row = chunk >> 3, cg = chunk & 7;
        uint4 vv = *(const uint4*)(cw + row * 72 + cg * 8);
        const int o = obase + w * 48 + m * 16 + row;
        const int n = nbase + cg * 8;
        *(uint4*)(pre + (((size_t)b * NC3 + o) << 14) + n) = vv;
      }
    }
    __syncthreads();  // scratch reads done before next ot's A stage
  }
}

// ---------------------------------------------------------------------------
// depthwise 3x3, 2 output rows x 8 px per thread (halo amp 3x -> 2x)
// + fused sum-of-squares for q,k planes.
// ---------------------------------------------------------------------------
__device__ __forceinline__ void dw_body(float* red, const u16* __restrict__ in,
                                        const float* __restrict__ wdw, u16* __restrict__ out,
                                        float* __restrict__ norms2, const int mod,
                                        const size_t t, const int tid) {
  const int l = tid & 63;
  const int xc = (int)(t & 15);
  const int yp = (int)((t >> 4) & 63);
  const int bc = (int)(t >> 10);
  const int c = bc % NC3;
  const int b = bc / NC3;
  const u16* p = in + ((size_t)bc << 14);
  const float* wc = wdw + c * 9;
  const int x0 = xc * 8;
  const int y0 = yp * 2;

  float a[4][10];
#pragma unroll
  for (int r = 0; r < 4; ++r) {
    const int y2 = y0 + r - 1;
    if ((unsigned)y2 < 128u) {
      const u16* row = p + (y2 << 7);
      uint4 v = *(const uint4*)(row + x0);
      a[r][1] = bf2f(v.x & 0xffff); a[r][2] = bf2f(v.x >> 16);
      a[r][3] = bf2f(v.y & 0xffff); a[r][4] = bf2f(v.y >> 16);
      a[r][5] = bf2f(v.z & 0xffff); a[r][6] = bf2f(v.z >> 16);
      a[r][7] = bf2f(v.w & 0xffff); a[r][8] = bf2f(v.w >> 16);
    } else {
#pragma unroll
      for (int j = 1; j < 9; ++j) a[r][j] = 0.f;
    }
    const float lf = __shfl(a[r][8], (l - 1) & 63, 64);
    const float rt = __shfl(a[r][1], (l + 1) & 63, 64);
    a[r][0] = (xc > 0) ? lf : 0.f;
    a[r][9] = (xc < 15) ? rt : 0.f;
  }
  const float w00 = wc[0], w01 = wc[1], w02 = wc[2];
  const float w10 = wc[3], w11 = wc[4], w12 = wc[5];
  const float w20 = wc[6], w21 = wc[7], w22 = wc[8];
  float ssq = 0.f;
#pragma unroll
  for (int nn = 0; nn < 2; ++nn) {
    u16 o[8];
#pragma unroll
    for (int j = 0; j < 8; ++j) {
      float s = a[nn][j] * w00;
      s = fmaf(a[nn][j + 1], w01, s);
      s = fmaf(a[nn][j + 2], w02, s);
      s = fmaf(a[nn + 1][j], w10, s);
      s = fmaf(a[nn + 1][j + 1], w11, s);
      s = fmaf(a[nn + 1][j + 2], w12, s);
      s = fmaf(a[nn + 2][j], w20, s);
      s = fmaf(a[nn + 2][j + 1], w21, s);
      s = fmaf(a[nn + 2][j + 2], w22, s);
      ssq = fmaf(s, s, ssq);
      o[j] = f2bf(s);
    }
    *(uint4*)(out + ((size_t)bc << 14) + ((y0 + nn) << 7) + x0) =
        make_uint4(pk2(o[0], o[1]), pk2(o[2], o[3]), pk2(o[4], o[5]), pk2(o[6], o[7]));
  }

  if (c < 384) {
#pragma unroll
    for (int off = 32; off > 0; off >>= 1) ssq += __shfl_down(ssq, off, 64);
    if ((tid & 63) == 0) red[tid >> 6] = ssq;
    __syncthreads();
    if (tid == 0) {
      const int tt = (c < 192) ? mod : 2 + mod;
      atomicAdd(&norms2[(tt * NB + b) * NCH + (c % NCH)], red[0] + red[1] + red[2] + red[3]);
    }
  }
}

__global__ __launch_bounds__(256) void dwconv_kernel(
    const u16* __restrict__ in, const float* __restrict__ wdw, u16* __restrict__ out,
    float* __restrict__ norms2, const int mod) {
  __shared__ float red[4];
  dw_body(red, in, wdw, out, norms2, mod,
          (size_t)blockIdx.x * 256 + threadIdx.x, threadIdx.x);
}

// merged both modalities (needs distinct qkv2 buffer): 36864 blocks.
__global__ __launch_bounds__(256) void dwm_kernel(
    const u16* __restrict__ pre1, const float* __restrict__ wdw1, u16* __restrict__ qkv1,
    const u16* __restrict__ pre2, const float* __restrict__ wdw2, u16* __restrict__ qkv2,
    float* __restrict__ norms2) {
  __shared__ float red[4];
  const size_t t = (size_t)blockIdx.x * 256 + threadIdx.x;
  const int bc = (int)(t >> 10);              // [0, 9216)
  const int mod = (bc >= NB * NC3) ? 1 : 0;
  const size_t tm = t - ((size_t)mod * NB * NC3 << 10);
  if (mod)
    dw_body(red, pre2, wdw2, qkv2, norms2, 1, tm, threadIdx.x);
  else
    dw_body(red, pre1, wdw1, qkv1, norms2, 0, tm, threadIdx.x);
}

// ---------------------------------------------------------------------------
// Gram via MFMA, fragments direct from global (NT: contraction over n).
// In-block 4-wave reduce, then atomicAdd partial into G.
// ---------------------------------------------------------------------------
__global__ __launch_bounds__(256) void gram_mfma_kernel(
    const u16* __restrict__ qkv1, const u16* __restrict__ qkv2, float* __restrict__ G) {
  const int nc = blockIdx.x, h = blockIdx.y, b = blockIdx.z;
  const int tid = threadIdx.x;
  const int w = tid >> 6, l = tid & 63;

  const u16* qp[3];
  const u16* kp[3];
#pragma unroll
  for (int m = 0; m < 3; ++m) {
    const int rq = m * 16 + (l & 15);
    const int cc = h * 24 + (rq < 24 ? rq : rq - 24);
    const u16* basep = (rq < 24) ? qkv1 : qkv2;
    qp[m] = basep + (((size_t)b * NC3 + cc) << 14);
    kp[m] = basep + (((size_t)b * NC3 + 192 + cc) << 14);
  }
  const int kbase = nc * 1024 + w * 256 + (l >> 4) * 8;

  f32x4 acc[3][3];
#pragma unroll
  for (int m = 0; m < 3; ++m)
#pragma unroll
    for (int nf = 0; nf < 3; ++nf) acc[m][nf] = (f32x4)0.f;

  for (int t = 0; t < 8; ++t) {
    const int ko = kbase + t * 32;
    s16x8 a[3], bv[3];
#pragma unroll
    for (int m = 0; m < 3; ++m) {
      a[m] = *(const s16x8*)(qp[m] + ko);
      bv[m] = *(const s16x8*)(kp[m] + ko);
    }
#pragma unroll
    for (int m = 0; m < 3; ++m)
#pragma unroll
      for (int nf = 0; nf < 3; ++nf)
        acc[m][nf] = __builtin_amdgcn_mfma_f32_16x16x32_bf16(a[m], bv[nf], acc[m][nf], 0, 0, 0);
  }

  __shared__ float red[4][48][48];
#pragma unroll
  for (int m = 0; m < 3; ++m)
#pragma unroll
    for (int nf = 0; nf < 3; ++nf)
#pragma unroll
      for (int r = 0; r < 4; ++r)
        red[w][m * 16 + (l >> 4) * 4 + r][nf * 16 + (l & 15)] = acc[m][nf][r];
  __syncthreads();
  float* dst = G + ((size_t)b * 8 + h) * 2304;
  for (int e = tid; e < 2304; e += 256) {
    const int rr = e / 48, cc = e % 48;
    atomicAdd(&dst[e], red[0][rr][cc] + red[1][rr][cc] + red[2][rr][cc] + red[3][rr][cc]);
  }
}

// ---------------------------------------------------------------------------
// softmax (4x 24x24 per b,h) + fused weights, bf16 output
// ---------------------------------------------------------------------------
__global__ __launch_bounds__(256) void softmax_wcat_kernel(
    const float* __restrict__ G, const float* __restrict__ norms2,
    const float* __restrict__ temperature, const float* __restrict__ beta,
    const float* __restrict__ wproj, u16* __restrict__ Wcat) {
  const int bh = blockIdx.x;
  const int b = bh >> 3, h = bh & 7;
  __shared__ float sm[4][24][24];
  __shared__ float nrm[4][24];
  const int tid = threadIdx.x;
  if (tid < 96) {
    int t = tid / 24, ci = tid % 24;
    nrm[t][ci] = fmaxf(sqrtf(norms2[(t * NB + b) * NCH + h * 24 + ci]), 1e-12f);
  }
  __syncthreads();
  const float T = temperature[h];
  const float sigB = 1.f / (1.f + expf(-beta[0]));
  if (tid < 96) {
    const int m = tid / 24, r = tid % 24;
    const float* Gb = G + (size_t)bh * 2304;
    const int gr = (m >= 2) ? 24 + r : r;
    const int gc0 = (m == 1 || m == 2) ? 24 : 0;
    const float* qn = (m >= 2) ? nrm[1] : nrm[0];
    const float* kn = (m == 1 || m == 2) ? nrm[3] : nrm[2];
    const float sign = (m == 0 || m == 2) ? 1.f : -1.f;
    const float qs = sign * T / qn[r];
    float L[24], mx = -1e30f;
#pragma unroll
    for (int cc = 0; cc < 24; ++cc) {
      L[cc] = Gb[gr * 48 + gc0 + cc] * qs / kn[cc];
      mx = fmaxf(mx, L[cc]);
    }
    float ssum = 0.f;
#pragma unroll
    for (int cc = 0; cc < 24; ++cc) {
      L[cc] = expf(L[cc] - mx);
      ssum += L[cc];
    }
    const float inv = 1.f / ssum;
#pragma unroll
    for (int cc = 0; cc < 24; ++cc) sm[m][r][cc] = L[cc] * inv;
  }
  __syncthreads();
  for (int e = tid; e < 384 * 48; e += 256) {
    const int o = e / 48, dc = e % 48;
    const int part = dc / 24, d = dc % 24;
    const int oc = (o < 192) ? o : o - 192;
    int m;
    float scale;
    if (o < 192) { m = part ? 1 : 0; scale = part ? 1.f : sigB; }
    else         { m = part ? 2 : 3; scale = part ? sigB : 1.f; }
    float s = 0.f;
#pragma unroll
    for (int ci = 0; ci < 24; ++ci) s += wproj[oc * 192 + h * 24 + ci] * sm[m][ci][d];
    Wcat[((size_t)b * 384 + o) * 384 + part * 192 + h * 24 + d] = f2bf(s * scale);
  }
}

// ---------------------------------------------------------------------------
// final GEMM MFMA: A (Wcat, L2-resident) dbuf 2x16KB; B single 16KB write-late.
// LDS total 48KB -> 3 blocks/CU. Non-temporal output stores.
// ---------------------------------------------------------------------------
__device__ __forceinline__ void fin_b_load(const u16* __restrict__ qkv1,
                                           const u16* __restrict__ qkv2,
                                           int b, int nbase, int kb, int w, int l,
                                           u32 (&val)[16]) {
  const u16* vbase = (kb < 192) ? qkv1 + (((size_t)b * NC3 + 384 + kb) << 14)
                                : qkv2 + (((size_t)b * NC3 + 384 + kb - 192) << 14);
  const u16* p0 = vbase + (((size_t)(w * 16)) << 14) + nbase + l * 2;
#pragma unroll
  for (int jj = 0; jj < 16; ++jj)
    val[jj] = *(const u32*)(p0 + ((size_t)jj << 14));
}

__device__ __forceinline__ void fin_b_write(char* smem, int w, int l,
                                            const u32 (&val)[16]) {
#pragma unroll
  for (int nn = 0; nn < 2; ++nn) {
    const int row = l * 2 + nn;
    u32 p[8];
#pragma unroll
    for (int q = 0; q < 8; ++q) {
      const u32 a = (val[2 * q] >> (nn * 16)) & 0xffffu;
      const u32 bb = (val[2 * q + 1] >> (nn * 16)) & 0xffffu;
      p[q] = a | (bb << 16);
    }
    char* base = smem + 32768 + row * 128;
    *(uint4*)(base + ((w * 32 + 0) ^ swz(row))) = make_uint4(p[0], p[1], p[2], p[3]);
    *(uint4*)(base + ((w * 32 + 16) ^ swz(row))) = make_uint4(p[4], p[5], p[6], p[7]);
  }
}

__device__ __forceinline__ void fin_a_glds(char* smem, const u16* __restrict__ Wcat,
                                           int b, int obase, int kb, int w, int l, int buf) {
#pragma unroll
  for (int i = 0; i < 4; ++i) {
    const int grp = i * 4 + w;
    const int row = grp * 8 + (l >> 3);
    const int cb = ((l & 7) * 16) ^ swz(row);
    const char* src = (const char*)Wcat + ((size_t)b * 384 + obase + row) * 768 + kb * 2 + cb;
    gl_lds16(src, smem + buf * 16384 + grp * 1024);
  }
}

__global__ __launch_bounds__(256) void final_mfma_kernel(
    const u16* __restrict__ qkv1, const u16* __restrict__ qkv2,
    const u16* __restrict__ Wcat, float* __restrict__ out) {
  __shared__ char smem[49152];
  const int bid = blockIdx.x;                      // 3072 blocks
  const int id = (bid & 7) * 384 + (bid >> 3);
  const int b = id / 384;
  const int rr2 = id % 384;
  const int nbase = (rr2 / 3) * 128;
  const int obase = (rr2 % 3) * 128;
  const int tid = threadIdx.x;
  const int w = tid >> 6, l = tid & 63;
  const int wr = w >> 1, wc = w & 1;

  f32x4 acc[4][4];
#pragma unroll
  for (int m = 0; m < 4; ++m)
#pragma unroll
    for (int nf = 0; nf < 4; ++nf) acc[m][nf] = (f32x4)0.f;

  u32 fV[16];
  fin_b_load(qkv1, qkv2, b, nbase, 0, w, l, fV);
  fin_a_glds(smem, Wcat, b, obase, 0, w, l, 0);
  fin_b_write(smem, w, l, fV);
  __syncthreads();

  for (int t = 0; t < 6; ++t) {
    const int cur = t & 1;
    const int nxt = cur ^ 1;
    if (t < 5) {
      fin_b_load(qkv1, qkv2, b, nbase, (t + 1) * 64, w, l, fV);  // issue early
      fin_a_glds(smem, Wcat, b, obase, (t + 1) * 64, w, l, nxt);
    }
#pragma unroll
    for (int kk = 0; kk < 2; ++kk) {
      s16x8 a[4], bv[4];
      const int cbk = kk * 64 + (l >> 4) * 16;
#pragma unroll
      for (int m = 0; m < 4; ++m) {
        const int rowA = wr * 64 + m * 16 + (l & 15);
        a[m] = *(const s16x8*)(smem + cur * 16384 + rowA * 128 + (cbk ^ swz(rowA)));
      }
#pragma unroll
      for (int nf = 0; nf < 4; ++nf) {
        const int rowB = wc * 64 + nf * 16 + (l & 15);
        bv[nf] = *(const s16x8*)(smem + 32768 + rowB * 128 + (cbk ^ swz(rowB)));
      }
#pragma unroll
      for (int m = 0; m < 4; ++m)
#pragma unroll
        for (int nf = 0; nf < 4; ++nf)
          acc[m][nf] = __builtin_amdgcn_mfma_f32_16x16x32_bf16(a[m], bv[nf], acc[m][nf], 0, 0, 0);
    }
    __syncthreads();               // all waves done reading B
    if (t < 5) {
      fin_b_write(smem, w, l, fV); // write late into the single B buffer
      __syncthreads();             // new B (and A[nxt]) ready
    }
  }
  // epilogue: per-wave LDS transpose ([16][68] f32), then nt float4 stores.
  float* cw = (float*)(smem + w * 4352);
#pragma unroll
  for (int m = 0; m < 4; ++m) {
#pragma unroll
    for (int nf = 0; nf < 4; ++nf)
#pragma unroll
      for (int r = 0; r < 4; ++r)
        cw[((l >> 4) * 4 + r) * 68 + nf * 16 + (l & 15)] = acc[m][nf][r];
#pragma unroll
    for (int p = 0; p < 4; ++p) {
      const int chunk = p * 64 + l;
      const int row = chunk >> 4, cg = chunk & 15;
      f32x4 v = *(const f32x4*)(cw + row * 68 + cg * 4);
      const int o = obase + wr * 64 + m * 16 + row;
      const int n = nbase + wc * 64 + cg * 4;
      float* dst = (o < 192) ? out + (((size_t)b * NCH + o) << 14) + n
                             : out + 25165824 + (((size_t)b * NCH + o - 192) << 14) + n;
      __builtin_nontemporal_store(v, (f32x4*)dst);
    }
  }
}

// ---------------------------------------------------------------------------
extern "C" void kernel_launch(void* const* d_in, const int* in_sizes, int n_in,
                              void* d_out, int out_size, void* d_ws, size_t ws_size,
                              hipStream_t stream) {
  (void)in_sizes; (void)n_in; (void)out_size;
  const float* x1 = (const float*)d_in[0];
  const float* x2 = (const float*)d_in[1];
  const float* w_qkv1 = (const float*)d_in[2];
  const float* w_dw1 = (const float*)d_in[3];
  const float* w_qkv2 = (const float*)d_in[4];
  const float* w_dw2 = (const float*)d_in[5];
  const float* w_proj = (const float*)d_in[6];
  const float* temperature = (const float*)d_in[7];
  const float* beta = (const float*)d_in[8];
  float* out = (float*)d_out;

  char* wsb = (char*)d_ws;
  const size_t BUF = 150994944;  // one 8x576x16384 bf16 plane set
  const bool big = ws_size >= 607395840;

  u16* pre1 = (u16*)(wsb);
  u16* qkv1 = (u16*)(wsb + BUF);
  u16* pre2 = (u16*)(wsb + 2 * BUF);
  u16* qkv2 = big ? (u16*)(wsb + 3 * BUF) : pre1;  // small ws: reuse pre1 after dw1
  char* tail = big ? (wsb + 4 * BUF) : (wsb + 3 * BUF);
  u16* wbf1 = (u16*)(tail);                 // 221,184
  u16* wbf2 = (u16*)(tail + 221184);        // 221,184
  float* norms2 = (float*)(tail + 442368);  // 24,576
  float* G = (float*)(tail + 466944);       // 589,824
  u16* WcatBf = (u16*)(tail + 1056768);     // 2,359,296 -> tail end 3,416,064

  const int dwblocks = (int)(((size_t)NB * NC3 * NHW) / (256 * 16));  // 18432

  wcast_kernel<<<576, 256, 0, stream>>>(w_qkv1, w_qkv2, wbf1, wbf2, norms2, G);
  conv_mfma_kernel<<<4096, 256, 0, stream>>>(x1, wbf1, pre1, x2, wbf2, pre2);
  if (big) {
    dwm_kernel<<<2 * dwblocks, 256, 0, stream>>>(pre1, w_dw1, qkv1, pre2, w_dw2, qkv2, norms2);
  } else {
    dwconv_kernel<<<dwblocks, 256, 0, stream>>>(pre1, w_dw1, qkv1, norms2, 0);
    dwconv_kernel<<<dwblocks, 256, 0, stream>>>(pre2, w_dw2, qkv2, norms2, 1);
  }
  gram_mfma_kernel<<<dim3(16, NHEADS, NB), 256, 0, stream>>>(qkv1, qkv2, G);
  softmax_wcat_kernel<<<NB * NHEADS, 256, 0, stream>>>(G, norms2, temperature, beta, w_proj, WcatBf);
  final_mfma_kernel<<<3072, 256, 0, stream>>>(qkv1, qkv2, WcatBf, out);
}